// Round 3
// baseline (2333.270 us; speedup 1.0000x reference)
//
#include <hip/hip_runtime.h>
#include <cstdio>
#include <cstdint>

// ---------------------------------------------------------------------------
// Fused WindowAttention: per block = 2 windows (64-row padded), 8 waves.
//   phase 1 (x3 head-groups of 4 heads): qkv partial GEMM (A=x staged LDS,
//     B=W_qkv direct-from-global frags) -> scatter Q/K/Vt to LDS (+bias,
//     Q*scale) -> per-wave attention (mask, softmax, PV) -> O to global (L2)
//   phase 2: proj GEMM (A=O restaged, B=W_proj direct) + bias -> fp32 out
// Shapes: B=4096 N=49 C=384 H=12 HD=32 NW=64.
// ---------------------------------------------------------------------------

typedef __attribute__((ext_vector_type(8))) short bfrag8;  // 8 bf16
typedef __attribute__((ext_vector_type(4))) float facc4;   // MFMA acc

#define SCALE_Q 0.17677669529663687f

__device__ __forceinline__ unsigned short f2bf(float f) {  // fp32->bf16 RNE
  unsigned int x = __float_as_uint(f);
  x += 0x7fffu + ((x >> 16) & 1u);
  return (unsigned short)(x >> 16);
}

__device__ __forceinline__ void gload_lds16(const void* g, void* l) {
  __builtin_amdgcn_global_load_lds(
      (const __attribute__((address_space(1))) unsigned int*)g,
      (__attribute__((address_space(3))) unsigned int*)l,
      16, 0, 0);
}

// ---- fp32 -> bf16, 4 elems/thread (counts are exact multiples of 1024) ----
__global__ void __launch_bounds__(256) cvt_bf16_kernel(const float* __restrict__ src,
                                                       unsigned short* __restrict__ dst) {
  size_t i = ((size_t)blockIdx.x * 256u + threadIdx.x) * 4u;
  const float4 v = *(const float4*)(src + i);
  ushort4 o;
  o.x = f2bf(v.x); o.y = f2bf(v.y); o.z = f2bf(v.z); o.w = f2bf(v.w);
  *(ushort4*)(dst + i) = o;
}

// ---------------------------------------------------------------------------
__global__ void __launch_bounds__(512) winattn_fused(
    const unsigned short* __restrict__ X,   // (4096*49, 384) bf16
    const unsigned short* __restrict__ Wq,  // (1152, 384) bf16
    const unsigned short* __restrict__ Wp,  // (384, 384) bf16
    const float* __restrict__ bq,           // (1152,)
    const float* __restrict__ bp,           // (384,)
    const float* __restrict__ maskg,        // (64, 49, 49)
    unsigned short* __restrict__ Og,        // (4096*49, 384) bf16 scratch
    float* __restrict__ out) {              // (4096*49, 384) fp32
  // LDS arena: As dbuf 2x16KB @0 | QK 64KB @32768 (per (wi,h): Q 4KB + K 4KB,
  // P aliases the 8KB after S) | Vt 32KB @98304 (per (wi,h): 4KB)
  __shared__ __align__(16) char lds[131072];
  char* Asb = lds;
  char* QK  = lds + 32768;
  char* VT  = lds + 98304;

  const int tid = threadIdx.x;
  const int lane = tid & 63, w = tid >> 6;
  const int l15 = lane & 15, l4 = lane >> 4;
  const int wi = w >> 2;       // window within block (0/1)
  const int wq4 = w & 3;       // col-quarter / head-lane
  const int b0 = blockIdx.x * 2;
  const int b = b0 + wi;
  const int wcol0 = wq4 * 96;

  const facc4 fz = {0.f, 0.f, 0.f, 0.f};
  const bfrag8 z8 = {0, 0, 0, 0, 0, 0, 0, 0};

  // staging map: 1024 16B chunks of a [128 rows][64 k] tile; 2 per thread.
  // LDS dest linear (chunk*16); global source pre-swizzled (scc = cc^(row&7)).
  size_t srow[2];
  int dstc[2];
#pragma unroll
  for (int i = 0; i < 2; ++i) {
    const int c = tid + (i << 9);
    const int row = c >> 3, cc = c & 7;
    const int scc = cc ^ (row & 7);
    const int rwi = row >> 6;
    int n = row & 63; if (n > 48) n = 48;        // clamp pad rows (finite dup)
    srow[i] = (size_t)((b0 + rwi) * 49 + n) * 384 + scc * 8;
    dstc[i] = c << 4;
  }

  // ---------------- phase 1: head-groups ----------------
  for (int hg = 0; hg < 3; ++hg) {
    // zero Vt (pad cols n in [49,64) must be 0 for PV)
    {
      char* p = VT + tid * 64;
#pragma unroll
      for (int j = 0; j < 4; ++j) *(bfrag8*)(p + j * 16) = z8;
    }

    // per-fragment B pointers / bias / scatter descriptors
    const unsigned short* bptr[6];
    float bv[6], scf[6];
    int stp[6];           // strip 0=Q 1=K 2=V
    char* dbase[6];       // LDS dest base per frag
    int d0v[6];
#pragma unroll
    for (int f = 0; f < 6; ++f) {
      const int vc0 = wcol0 + f * 16;
      const int s = vc0 >> 7;
      const int c0 = vc0 & 127;
      const int hl = c0 >> 5;
      const int gcol = s * 384 + hg * 128 + c0 + l15;
      bptr[f] = Wq + (size_t)gcol * 384;
      bv[f] = bq[gcol];
      scf[f] = (s == 0) ? SCALE_Q : 1.0f;
      stp[f] = s;
      d0v[f] = c0 & 31;
      if (s < 2) dbase[f] = QK + (size_t)(wi * 4 + hl) * 8192 + s * 4096;
      else       dbase[f] = VT + (size_t)(wi * 4 + hl) * 4096;
    }

    facc4 acc[4][6];
#pragma unroll
    for (int mi = 0; mi < 4; ++mi)
#pragma unroll
      for (int f = 0; f < 6; ++f) acc[mi][f] = fz;

    // K-loop, double-buffered, stage-before-compute
    int cur = 0;
#pragma unroll
    for (int i = 0; i < 2; ++i) gload_lds16(X + srow[i], Asb + dstc[i]);
    __syncthreads();
    for (int kt = 0; kt < 6; ++kt) {
      if (kt < 5) {
#pragma unroll
        for (int i = 0; i < 2; ++i)
          gload_lds16(X + srow[i] + (kt + 1) * 64, Asb + ((cur ^ 1) << 14) + dstc[i]);
      }
#pragma unroll
      for (int kk = 0; kk < 2; ++kk) {
        bfrag8 bf[6], af[4];
#pragma unroll
        for (int f = 0; f < 6; ++f)
          bf[f] = *(const bfrag8*)(bptr[f] + kt * 64 + kk * 32 + l4 * 8);
#pragma unroll
        for (int mi = 0; mi < 4; ++mi) {
          const int row = wi * 64 + mi * 16 + l15;
          af[mi] = *(const bfrag8*)(Asb + (cur << 14) + row * 128 +
                                    (((kk * 4 + l4) ^ (row & 7)) << 4));
        }
#pragma unroll
        for (int mi = 0; mi < 4; ++mi)
#pragma unroll
          for (int f = 0; f < 6; ++f)
            acc[mi][f] = __builtin_amdgcn_mfma_f32_16x16x32_bf16(af[mi], bf[f],
                                                                 acc[mi][f], 0, 0, 0);
      }
      __syncthreads();
      cur ^= 1;
    }

    // scatter to Qs / Ks / Vt  (acc: row m = mi*16+l4*4+r, col = l15 of frag)
#pragma unroll
    for (int f = 0; f < 6; ++f) {
      const int s = stp[f];
      const int d = d0v[f] + l15;
#pragma unroll
      for (int mi = 0; mi < 4; ++mi)
#pragma unroll
        for (int r = 0; r < 4; ++r) {
          const int m = mi * 16 + l4 * 4 + r;
          const float val = (acc[mi][f][r] + bv[f]) * scf[f];
          if (s < 2) {
            *(unsigned short*)(dbase[f] + m * 64 +
                               ((d << 1) ^ ((m & 3) << 4))) = f2bf(val);
          } else if (m < 49) {
            *(unsigned short*)(dbase[f] + d * 128 +
                               ((m << 1) ^ ((d & 7) << 4))) = f2bf(val);
          }
        }
    }
    __syncthreads();

    // ---------------- attention: wave -> (window wi, head hg*4+wq4) --------
    {
      char* qb = QK + (size_t)(wi * 4 + wq4) * 8192;
      char* kb = qb + 4096;
      char* vtb = VT + (size_t)(wi * 4 + wq4) * 4096;
      char* pb = qb;  // P aliases Q+K (8KB) after S is computed
      const int h = hg * 4 + wq4;

      facc4 s[4][4];
      {
        bfrag8 qa[4], kf[4];
#pragma unroll
        for (int mi = 0; mi < 4; ++mi) {
          const int row = mi * 16 + l15;
          qa[mi] = *(const bfrag8*)(qb + row * 64 + (((l4 ^ (row & 3))) << 4));
        }
#pragma unroll
        for (int ni = 0; ni < 4; ++ni) {
          const int row = ni * 16 + l15;
          kf[ni] = *(const bfrag8*)(kb + row * 64 + (((l4 ^ (row & 3))) << 4));
        }
#pragma unroll
        for (int mi = 0; mi < 4; ++mi)
#pragma unroll
          for (int ni = 0; ni < 4; ++ni)
            s[mi][ni] = __builtin_amdgcn_mfma_f32_16x16x32_bf16(qa[mi], kf[ni], fz, 0, 0, 0);
      }

      const float* mp = maskg + (size_t)(b & 63) * 2401;
      float rinv[4][4];
#pragma unroll
      for (int mi = 0; mi < 4; ++mi)
#pragma unroll
        for (int r = 0; r < 4; ++r) {
          const int m = mi * 16 + l4 * 4 + r;
          float mx = -1e30f;
#pragma unroll
          for (int ni = 0; ni < 4; ++ni) {
            const int n = ni * 16 + l15;
            const float add = (m < 49 && n < 49) ? mp[m * 49 + n] : -1e30f;
            const float v = s[mi][ni][r] + add;
            s[mi][ni][r] = v;
            mx = fmaxf(mx, v);
          }
          mx = fmaxf(mx, __shfl_xor(mx, 1));
          mx = fmaxf(mx, __shfl_xor(mx, 2));
          mx = fmaxf(mx, __shfl_xor(mx, 4));
          mx = fmaxf(mx, __shfl_xor(mx, 8));
          float sum = 0.f;
#pragma unroll
          for (int ni = 0; ni < 4; ++ni) {
            const float p = __expf(s[mi][ni][r] - mx);
            s[mi][ni][r] = p;
            sum += p;
          }
          sum += __shfl_xor(sum, 1);
          sum += __shfl_xor(sum, 2);
          sum += __shfl_xor(sum, 4);
          sum += __shfl_xor(sum, 8);
          rinv[mi][r] = 1.0f / sum;
#pragma unroll
          for (int ni = 0; ni < 4; ++ni) {
            const int n = ni * 16 + l15;
            *(unsigned short*)(pb + (((m << 7) + (n << 1)) ^ ((m & 7) << 4))) =
                f2bf(s[mi][ni][r]);
          }
        }

      facc4 o[4][2];
#pragma unroll
      for (int mi = 0; mi < 4; ++mi)
#pragma unroll
        for (int di = 0; di < 2; ++di) o[mi][di] = fz;
#pragma unroll
      for (int kk = 0; kk < 2; ++kk) {
        bfrag8 pa[4], vb[2];
#pragma unroll
        for (int mi = 0; mi < 4; ++mi) {
          const int row = mi * 16 + l15;
          pa[mi] = *(const bfrag8*)(pb + (((row << 7) + kk * 64 + (l4 << 4)) ^
                                          ((row & 7) << 4)));
        }
#pragma unroll
        for (int di = 0; di < 2; ++di) {
          const int row = di * 16 + l15;
          vb[di] = *(const bfrag8*)(vtb + (((row << 7) + kk * 64 + (l4 << 4)) ^
                                           ((row & 7) << 4)));
        }
#pragma unroll
        for (int mi = 0; mi < 4; ++mi)
#pragma unroll
          for (int di = 0; di < 2; ++di)
            o[mi][di] = __builtin_amdgcn_mfma_f32_16x16x32_bf16(pa[mi], vb[di],
                                                                o[mi][di], 0, 0, 0);
      }

      unsigned short* op = Og + ((size_t)b * 49) * 384 + h * 32;
#pragma unroll
      for (int mi = 0; mi < 4; ++mi)
#pragma unroll
        for (int r = 0; r < 4; ++r) {
          const int m = mi * 16 + l4 * 4 + r;
          if (m < 49) {
            const float rs = rinv[mi][r];
#pragma unroll
            for (int di = 0; di < 2; ++di)
              op[(size_t)m * 384 + di * 16 + l15] = f2bf(o[mi][di][r] * rs);
          }
        }
    }
    __syncthreads();  // drains O writes; protects Q/K/Vt reuse next hg
  }

  // ---------------- phase 2: proj GEMM ----------------
  {
    const unsigned short* cptr[6];
    float bpv[6];
#pragma unroll
    for (int f = 0; f < 6; ++f) {
      const int c = wcol0 + f * 16 + l15;
      cptr[f] = Wp + (size_t)c * 384;
      bpv[f] = bp[c];
    }
    facc4 acc[4][6];
#pragma unroll
    for (int mi = 0; mi < 4; ++mi)
#pragma unroll
      for (int f = 0; f < 6; ++f) acc[mi][f] = fz;

    int cur = 0;
#pragma unroll
    for (int i = 0; i < 2; ++i) gload_lds16(Og + srow[i], Asb + dstc[i]);
    __syncthreads();
    for (int kt = 0; kt < 6; ++kt) {
      if (kt < 5) {
#pragma unroll
        for (int i = 0; i < 2; ++i)
          gload_lds16(Og + srow[i] + (kt + 1) * 64, Asb + ((cur ^ 1) << 14) + dstc[i]);
      }
#pragma unroll
      for (int kk = 0; kk < 2; ++kk) {
        bfrag8 bf[6], af[4];
#pragma unroll
        for (int f = 0; f < 6; ++f)
          bf[f] = *(const bfrag8*)(cptr[f] + kt * 64 + kk * 32 + l4 * 8);
#pragma unroll
        for (int mi = 0; mi < 4; ++mi) {
          const int row = wi * 64 + mi * 16 + l15;
          af[mi] = *(const bfrag8*)(Asb + (cur << 14) + row * 128 +
                                    (((kk * 4 + l4) ^ (row & 7)) << 4));
        }
#pragma unroll
        for (int mi = 0; mi < 4; ++mi)
#pragma unroll
          for (int f = 0; f < 6; ++f)
            acc[mi][f] = __builtin_amdgcn_mfma_f32_16x16x32_bf16(af[mi], bf[f],
                                                                 acc[mi][f], 0, 0, 0);
      }
      __syncthreads();
      cur ^= 1;
    }

#pragma unroll
    for (int mi = 0; mi < 4; ++mi)
#pragma unroll
      for (int r = 0; r < 4; ++r) {
        const int n = mi * 16 + l4 * 4 + r;
        if (n < 49) {
          float* orow = out + ((size_t)b * 49 + n) * 384 + wcol0 + l15;
#pragma unroll
          for (int f = 0; f < 6; ++f) orow[f * 16] = acc[mi][f][r] + bpv[f];
        }
      }
  }
}

// ---------------------------------------------------------------------------
extern "C" void kernel_launch(void* const* d_in, const int* in_sizes, int n_in,
                              void* d_out, int out_size, void* d_ws, size_t ws_size,
                              hipStream_t stream) {
  const float* x      = (const float*)d_in[0];  // (4096, 49, 384)
  const float* mask   = (const float*)d_in[1];  // (64, 49, 49)
  const float* w_qkv  = (const float*)d_in[2];  // (1152, 384)
  const float* b_qkv  = (const float*)d_in[3];  // (1152,)
  const float* w_proj = (const float*)d_in[4];  // (384, 384)
  const float* b_proj = (const float*)d_in[5];  // (384,)
  float* out = (float*)d_out;

  const size_t E = 77070336ull;  // 200704*384
  unsigned short* wsu  = (unsigned short*)d_ws;
  unsigned short* o_ws = wsu;            // (200704, 384) bf16
  unsigned short* xbf  = wsu + E;        // (200704, 384) bf16
  unsigned short* wqb  = wsu + 2 * E;    // (1152, 384) bf16
  unsigned short* wpb  = wqb + 442368ull;
  const size_t need = (2 * E + 442368ull + 147456ull) * 2ull;
  if (ws_size < need) {
    fprintf(stderr, "[WindowAttention] ws too small: need=%zu have=%zu\n",
            (size_t)need, ws_size);
    return;
  }

  cvt_bf16_kernel<<<75264, 256, 0, stream>>>(x, xbf);
  cvt_bf16_kernel<<<432, 256, 0, stream>>>(w_qkv, wqb);
  cvt_bf16_kernel<<<144, 256, 0, stream>>>(w_proj, wpb);

  winattn_fused<<<2048, 512, 0, stream>>>(xbf, wqb, wpb, b_qkv, b_proj, mask,
                                          o_ws, out);
}

// Round 4
// 2018.132 us; speedup vs baseline: 1.1562x; 1.1562x over previous
//
#include <hip/hip_runtime.h>
#include <cstdio>
#include <cstdint>

// ---------------------------------------------------------------------------
// Fused WindowAttention: per block = 2 windows (64-row padded), 8 waves.
//   phase 1 (x3 head-groups of 4 heads): qkv partial GEMM (A=x staged LDS,
//     B=W_qkv direct-from-global frags) -> scatter Q/K/Vt to LDS (+bias,
//     Q*scale) -> per-wave attention (bitmask, softmax, PV) -> O to global
//   phase 2: proj GEMM (A=O restaged, B=W_proj direct) + bias -> fp32 out
// Round-4 fixes vs round-3: __launch_bounds__(512,2) (kill acc spills),
// readfirstlane wave-uniform LDS dest for global_load_lds, bitmask mask.
// ---------------------------------------------------------------------------

typedef __attribute__((ext_vector_type(8))) short bfrag8;  // 8 bf16
typedef __attribute__((ext_vector_type(4))) float facc4;   // MFMA acc

#define SCALE_Q 0.17677669529663687f

__device__ __forceinline__ unsigned short f2bf(float f) {  // fp32->bf16 RNE
  unsigned int x = __float_as_uint(f);
  x += 0x7fffu + ((x >> 16) & 1u);
  return (unsigned short)(x >> 16);
}

__device__ __forceinline__ void gload_lds16(const void* g, void* l) {
  __builtin_amdgcn_global_load_lds(
      (const __attribute__((address_space(1))) unsigned int*)g,
      (__attribute__((address_space(3))) unsigned int*)l,
      16, 0, 0);
}

// ---- fp32 -> bf16, 4 elems/thread (counts are exact multiples of 1024) ----
__global__ void __launch_bounds__(256) cvt_bf16_kernel(const float* __restrict__ src,
                                                       unsigned short* __restrict__ dst) {
  size_t i = ((size_t)blockIdx.x * 256u + threadIdx.x) * 4u;
  const float4 v = *(const float4*)(src + i);
  ushort4 o;
  o.x = f2bf(v.x); o.y = f2bf(v.y); o.z = f2bf(v.z); o.w = f2bf(v.w);
  *(ushort4*)(dst + i) = o;
}

// ---- mask -> per-row 49-bit allow mask (64 windows x 64 rows, pads=0) -----
__global__ void __launch_bounds__(256) mask_bits_kernel(
    const float* __restrict__ mask, unsigned long long* __restrict__ bits) {
  const int idx = blockIdx.x * 256 + threadIdx.x;  // 0..4095
  const int wdw = idx >> 6, m = idx & 63;
  unsigned long long bm = 0ull;
  if (m < 49) {
    const float* mp = mask + (size_t)wdw * 2401 + (size_t)m * 49;
    for (int n = 0; n < 49; ++n)
      if (mp[n] > -50.f) bm |= (1ull << n);
  }
  bits[idx] = bm;
}

// ---------------------------------------------------------------------------
__global__ void __launch_bounds__(512, 2) winattn_fused(
    const unsigned short* __restrict__ X,   // (4096*49, 384) bf16
    const unsigned short* __restrict__ Wq,  // (1152, 384) bf16
    const unsigned short* __restrict__ Wp,  // (384, 384) bf16
    const float* __restrict__ bq,           // (1152,)
    const float* __restrict__ bp,           // (384,)
    const unsigned long long* __restrict__ mbits,  // (64, 64) row bitmasks
    unsigned short* __restrict__ Og,        // (4096*49, 384) bf16 scratch
    float* __restrict__ out) {              // (4096*49, 384) fp32
  // LDS arena: As dbuf 2x16KB @0 | QK 64KB @32768 (per (wi,h): Q 4KB + K 4KB,
  // P aliases the 8KB after S) | Vt 32KB @98304 (per (wi,h): 4KB)
  __shared__ __align__(16) char lds[131072];
  char* Asb = lds;
  char* QK  = lds + 32768;
  char* VT  = lds + 98304;

  const int tid = threadIdx.x;
  const int lane = tid & 63, w = tid >> 6;
  const int l15 = lane & 15, l4 = lane >> 4;
  const int wi = w >> 2;       // window within block (0/1)
  const int wq4 = w & 3;       // col-quarter / head-lane
  const int b0 = blockIdx.x * 2;
  const int b = b0 + wi;
  const int wcol0 = wq4 * 96;

  const facc4 fz = {0.f, 0.f, 0.f, 0.f};
  const bfrag8 z8 = {0, 0, 0, 0, 0, 0, 0, 0};

  // staging map: 1024 16B chunks of a [128 rows][64 k] tile; 2 per thread.
  // HW: LDS dest = wave-uniform base + lane*16 -> chunk c = w*64 + i*512 + lane.
  // Global source is per-lane, pre-swizzled (scc = cc ^ (row&7)).
  size_t srow[2];
#pragma unroll
  for (int i = 0; i < 2; ++i) {
    const int c = tid + (i << 9);
    const int row = c >> 3, cc = c & 7;
    const int scc = cc ^ (row & 7);
    const int rwi = row >> 6;
    int n = row & 63; if (n > 48) n = 48;        // clamp pad rows (finite dup)
    srow[i] = (size_t)((b0 + rwi) * 49 + n) * 384 + scc * 8;
  }

  // ---------------- phase 1: head-groups ----------------
  for (int hg = 0; hg < 3; ++hg) {
    // zero Vt (pad cols n in [49,64) must be 0 for PV)
    {
      char* p = VT + tid * 64;
#pragma unroll
      for (int j = 0; j < 4; ++j) *(bfrag8*)(p + j * 16) = z8;
    }

    // per-fragment B pointers / bias / scatter descriptors
    const unsigned short* bptr[6];
    float bv[6], scf[6];
    int stp[6];           // strip 0=Q 1=K 2=V
    char* dbase[6];       // LDS dest base per frag
    int d0v[6];
#pragma unroll
    for (int f = 0; f < 6; ++f) {
      const int vc0 = wcol0 + f * 16;
      const int s = vc0 >> 7;
      const int c0 = vc0 & 127;
      const int hl = c0 >> 5;
      const int gcol = s * 384 + hg * 128 + c0 + l15;
      bptr[f] = Wq + (size_t)gcol * 384;
      bv[f] = bq[gcol];
      scf[f] = (s == 0) ? SCALE_Q : 1.0f;
      stp[f] = s;
      d0v[f] = c0 & 31;
      if (s < 2) dbase[f] = QK + (size_t)(wi * 4 + hl) * 8192 + s * 4096;
      else       dbase[f] = VT + (size_t)(wi * 4 + hl) * 4096;
    }

    facc4 acc[4][6];
#pragma unroll
    for (int mi = 0; mi < 4; ++mi)
#pragma unroll
      for (int f = 0; f < 6; ++f) acc[mi][f] = fz;

    // K-loop, double-buffered, stage-before-compute
    int cur = 0;
#pragma unroll
    for (int i = 0; i < 2; ++i) {
      const int lb = __builtin_amdgcn_readfirstlane((w << 10) + (i << 13));
      gload_lds16(X + srow[i], Asb + lb);
    }
    __syncthreads();
    for (int kt = 0; kt < 6; ++kt) {
      if (kt < 5) {
#pragma unroll
        for (int i = 0; i < 2; ++i) {
          const int lb = __builtin_amdgcn_readfirstlane(
              ((cur ^ 1) << 14) + (w << 10) + (i << 13));
          gload_lds16(X + srow[i] + (kt + 1) * 64, Asb + lb);
        }
      }
#pragma unroll
      for (int kk = 0; kk < 2; ++kk) {
        bfrag8 bf[6], af[4];
#pragma unroll
        for (int f = 0; f < 6; ++f)
          bf[f] = *(const bfrag8*)(bptr[f] + kt * 64 + kk * 32 + l4 * 8);
#pragma unroll
        for (int mi = 0; mi < 4; ++mi) {
          const int row = wi * 64 + mi * 16 + l15;
          af[mi] = *(const bfrag8*)(Asb + (cur << 14) + row * 128 +
                                    (((kk * 4 + l4) ^ (row & 7)) << 4));
        }
#pragma unroll
        for (int mi = 0; mi < 4; ++mi)
#pragma unroll
          for (int f = 0; f < 6; ++f)
            acc[mi][f] = __builtin_amdgcn_mfma_f32_16x16x32_bf16(af[mi], bf[f],
                                                                 acc[mi][f], 0, 0, 0);
      }
      __syncthreads();
      cur ^= 1;
    }

    // scatter to Qs / Ks / Vt  (acc: row m = mi*16+l4*4+r, col = l15 of frag)
#pragma unroll
    for (int f = 0; f < 6; ++f) {
      const int s = stp[f];
      const int d = d0v[f] + l15;
#pragma unroll
      for (int mi = 0; mi < 4; ++mi)
#pragma unroll
        for (int r = 0; r < 4; ++r) {
          const int m = mi * 16 + l4 * 4 + r;
          const float val = (acc[mi][f][r] + bv[f]) * scf[f];
          if (s < 2) {
            *(unsigned short*)(dbase[f] + m * 64 +
                               ((d << 1) ^ ((m & 3) << 4))) = f2bf(val);
          } else if (m < 49) {
            *(unsigned short*)(dbase[f] + d * 128 +
                               ((m << 1) ^ ((d & 7) << 4))) = f2bf(val);
          }
        }
    }
    __syncthreads();

    // ---------------- attention: wave -> (window wi, head hg*4+wq4) --------
    {
      char* qb = QK + (size_t)(wi * 4 + wq4) * 8192;
      char* kb = qb + 4096;
      char* vtb = VT + (size_t)(wi * 4 + wq4) * 4096;
      char* pb = qb;  // P aliases Q+K (8KB) after S is computed
      const int h = hg * 4 + wq4;

      facc4 s[4][4];
      {
        bfrag8 qa[4], kf[4];
#pragma unroll
        for (int mi = 0; mi < 4; ++mi) {
          const int row = mi * 16 + l15;
          qa[mi] = *(const bfrag8*)(qb + row * 64 + (((l4 ^ (row & 3))) << 4));
        }
#pragma unroll
        for (int ni = 0; ni < 4; ++ni) {
          const int row = ni * 16 + l15;
          kf[ni] = *(const bfrag8*)(kb + row * 64 + (((l4 ^ (row & 3))) << 4));
        }
#pragma unroll
        for (int mi = 0; mi < 4; ++mi)
#pragma unroll
          for (int ni = 0; ni < 4; ++ni)
            s[mi][ni] = __builtin_amdgcn_mfma_f32_16x16x32_bf16(qa[mi], kf[ni], fz, 0, 0, 0);
      }

      const unsigned long long* mb = mbits + (size_t)(b & 63) * 64;
      float rinv[4][4];
#pragma unroll
      for (int mi = 0; mi < 4; ++mi)
#pragma unroll
        for (int r = 0; r < 4; ++r) {
          const int m = mi * 16 + l4 * 4 + r;
          const unsigned long long mw = mb[m];
          float mx = -1e30f;
          int ok[4];
#pragma unroll
          for (int ni = 0; ni < 4; ++ni) {
            const int n = ni * 16 + l15;
            ok[ni] = (int)((mw >> n) & 1ull);
            const float v = ok[ni] ? s[mi][ni][r] : -1e30f;
            mx = fmaxf(mx, v);
          }
          mx = fmaxf(mx, __shfl_xor(mx, 1));
          mx = fmaxf(mx, __shfl_xor(mx, 2));
          mx = fmaxf(mx, __shfl_xor(mx, 4));
          mx = fmaxf(mx, __shfl_xor(mx, 8));
          float sum = 0.f;
#pragma unroll
          for (int ni = 0; ni < 4; ++ni) {
            const float p = ok[ni] ? __expf(s[mi][ni][r] - mx) : 0.f;
            s[mi][ni][r] = p;
            sum += p;
          }
          sum += __shfl_xor(sum, 1);
          sum += __shfl_xor(sum, 2);
          sum += __shfl_xor(sum, 4);
          sum += __shfl_xor(sum, 8);
          rinv[mi][r] = 1.0f / sum;
#pragma unroll
          for (int ni = 0; ni < 4; ++ni) {
            const int n = ni * 16 + l15;
            *(unsigned short*)(pb + (((m << 7) + (n << 1)) ^ ((m & 7) << 4))) =
                f2bf(s[mi][ni][r]);
          }
        }

      facc4 o[4][2];
#pragma unroll
      for (int mi = 0; mi < 4; ++mi)
#pragma unroll
        for (int di = 0; di < 2; ++di) o[mi][di] = fz;
#pragma unroll
      for (int kk = 0; kk < 2; ++kk) {
        bfrag8 pa[4], vb[2];
#pragma unroll
        for (int mi = 0; mi < 4; ++mi) {
          const int row = mi * 16 + l15;
          pa[mi] = *(const bfrag8*)(pb + (((row << 7) + kk * 64 + (l4 << 4)) ^
                                          ((row & 7) << 4)));
        }
#pragma unroll
        for (int di = 0; di < 2; ++di) {
          const int row = di * 16 + l15;
          vb[di] = *(const bfrag8*)(vtb + (((row << 7) + kk * 64 + (l4 << 4)) ^
                                           ((row & 7) << 4)));
        }
#pragma unroll
        for (int mi = 0; mi < 4; ++mi)
#pragma unroll
          for (int di = 0; di < 2; ++di)
            o[mi][di] = __builtin_amdgcn_mfma_f32_16x16x32_bf16(pa[mi], vb[di],
                                                                o[mi][di], 0, 0, 0);
      }

      unsigned short* op = Og + ((size_t)b * 49) * 384 + h * 32;
#pragma unroll
      for (int mi = 0; mi < 4; ++mi)
#pragma unroll
        for (int r = 0; r < 4; ++r) {
          const int m = mi * 16 + l4 * 4 + r;
          if (m < 49) {
            const float rs = rinv[mi][r];
#pragma unroll
            for (int di = 0; di < 2; ++di)
              op[(size_t)m * 384 + di * 16 + l15] = f2bf(o[mi][di][r] * rs);
          }
        }
    }
    __syncthreads();  // drains O writes; protects Q/K/Vt reuse next hg
  }

  // ---------------- phase 2: proj GEMM ----------------
  {
    const unsigned short* cptr[6];
    float bpv[6];
#pragma unroll
    for (int f = 0; f < 6; ++f) {
      const int c = wcol0 + f * 16 + l15;
      cptr[f] = Wp + (size_t)c * 384;
      bpv[f] = bp[c];
    }
    facc4 acc[4][6];
#pragma unroll
    for (int mi = 0; mi < 4; ++mi)
#pragma unroll
      for (int f = 0; f < 6; ++f) acc[mi][f] = fz;

    int cur = 0;
#pragma unroll
    for (int i = 0; i < 2; ++i) {
      const int lb = __builtin_amdgcn_readfirstlane((w << 10) + (i << 13));
      gload_lds16(Og + srow[i], Asb + lb);
    }
    __syncthreads();
    for (int kt = 0; kt < 6; ++kt) {
      if (kt < 5) {
#pragma unroll
        for (int i = 0; i < 2; ++i) {
          const int lb = __builtin_amdgcn_readfirstlane(
              ((cur ^ 1) << 14) + (w << 10) + (i << 13));
          gload_lds16(Og + srow[i] + (kt + 1) * 64, Asb + lb);
        }
      }
#pragma unroll
      for (int kk = 0; kk < 2; ++kk) {
        bfrag8 bf[6], af[4];
#pragma unroll
        for (int f = 0; f < 6; ++f)
          bf[f] = *(const bfrag8*)(cptr[f] + kt * 64 + kk * 32 + l4 * 8);
#pragma unroll
        for (int mi = 0; mi < 4; ++mi) {
          const int row = wi * 64 + mi * 16 + l15;
          af[mi] = *(const bfrag8*)(Asb + (cur << 14) + row * 128 +
                                    (((kk * 4 + l4) ^ (row & 7)) << 4));
        }
#pragma unroll
        for (int mi = 0; mi < 4; ++mi)
#pragma unroll
          for (int f = 0; f < 6; ++f)
            acc[mi][f] = __builtin_amdgcn_mfma_f32_16x16x32_bf16(af[mi], bf[f],
                                                                 acc[mi][f], 0, 0, 0);
      }
      __syncthreads();
      cur ^= 1;
    }

#pragma unroll
    for (int mi = 0; mi < 4; ++mi)
#pragma unroll
      for (int r = 0; r < 4; ++r) {
        const int n = mi * 16 + l4 * 4 + r;
        if (n < 49) {
          float* orow = out + ((size_t)b * 49 + n) * 384 + wcol0 + l15;
#pragma unroll
          for (int f = 0; f < 6; ++f) orow[f * 16] = acc[mi][f][r] + bpv[f];
        }
      }
  }
}

// ---------------------------------------------------------------------------
extern "C" void kernel_launch(void* const* d_in, const int* in_sizes, int n_in,
                              void* d_out, int out_size, void* d_ws, size_t ws_size,
                              hipStream_t stream) {
  const float* x      = (const float*)d_in[0];  // (4096, 49, 384)
  const float* mask   = (const float*)d_in[1];  // (64, 49, 49)
  const float* w_qkv  = (const float*)d_in[2];  // (1152, 384)
  const float* b_qkv  = (const float*)d_in[3];  // (1152,)
  const float* w_proj = (const float*)d_in[4];  // (384, 384)
  const float* b_proj = (const float*)d_in[5];  // (384,)
  float* out = (float*)d_out;

  const size_t E = 77070336ull;  // 200704*384
  unsigned short* wsu  = (unsigned short*)d_ws;
  unsigned short* o_ws = wsu;            // (200704, 384) bf16
  unsigned short* xbf  = wsu + E;        // (200704, 384) bf16
  unsigned short* wqb  = wsu + 2 * E;    // (1152, 384) bf16
  unsigned short* wpb  = wqb + 442368ull;
  unsigned long long* mb = (unsigned long long*)(wpb + 147456ull);  // 4096 u64
  const size_t need = (2 * E + 442368ull + 147456ull) * 2ull + 4096ull * 8ull;
  if (ws_size < need) {
    fprintf(stderr, "[WindowAttention] ws too small: need=%zu have=%zu\n",
            (size_t)need, ws_size);
    return;
  }

  cvt_bf16_kernel<<<75264, 256, 0, stream>>>(x, xbf);
  cvt_bf16_kernel<<<432, 256, 0, stream>>>(w_qkv, wqb);
  cvt_bf16_kernel<<<144, 256, 0, stream>>>(w_proj, wpb);
  mask_bits_kernel<<<16, 256, 0, stream>>>(mask, mb);

  winattn_fused<<<2048, 512, 0, stream>>>(xbf, wqb, wpb, b_qkv, b_proj, mb,
                                          o_ws, out);
}

// Round 5
// 2016.276 us; speedup vs baseline: 1.1572x; 1.0009x over previous
//
#include <hip/hip_runtime.h>
#include <cstdio>
#include <cstdint>

// ---------------------------------------------------------------------------
// Fused WindowAttention: per block = 2 windows (64-row padded), 8 waves.
//   phase 1 (x3 head-groups of 4 heads): qkv partial GEMM (A=x staged LDS,
//     B=W_qkv direct-from-global frags) -> scatter Q/K/Vt to LDS (+bias,
//     Q*scale) -> per-wave attention (bitmask, softmax, PV) -> O to global
//   phase 2: proj GEMM (A=O restaged, B=W_proj direct) + bias -> fp32 out
// Round-5 fix: __launch_bounds__(512, 1). The 2nd arg acts as min BLOCKS/CU
// (CUDA semantics in hipcc): (512,2) capped VGPR at 128 -> acc spilled to
// scratch (observed: +0.8GB write, +1.0GB fetch vs ideal). LDS=128KB already
// limits residency to 1 block/CU, so ask for exactly that -> 256-VGPR budget.
// ---------------------------------------------------------------------------

typedef __attribute__((ext_vector_type(8))) short bfrag8;  // 8 bf16
typedef __attribute__((ext_vector_type(4))) float facc4;   // MFMA acc

#define SCALE_Q 0.17677669529663687f

__device__ __forceinline__ unsigned short f2bf(float f) {  // fp32->bf16 RNE
  unsigned int x = __float_as_uint(f);
  x += 0x7fffu + ((x >> 16) & 1u);
  return (unsigned short)(x >> 16);
}

__device__ __forceinline__ void gload_lds16(const void* g, void* l) {
  __builtin_amdgcn_global_load_lds(
      (const __attribute__((address_space(1))) unsigned int*)g,
      (__attribute__((address_space(3))) unsigned int*)l,
      16, 0, 0);
}

// ---- fp32 -> bf16, 4 elems/thread (counts are exact multiples of 1024) ----
__global__ void __launch_bounds__(256) cvt_bf16_kernel(const float* __restrict__ src,
                                                       unsigned short* __restrict__ dst) {
  size_t i = ((size_t)blockIdx.x * 256u + threadIdx.x) * 4u;
  const float4 v = *(const float4*)(src + i);
  ushort4 o;
  o.x = f2bf(v.x); o.y = f2bf(v.y); o.z = f2bf(v.z); o.w = f2bf(v.w);
  *(ushort4*)(dst + i) = o;
}

// ---- mask -> per-row 49-bit allow mask (64 windows x 64 rows, pads=0) -----
__global__ void __launch_bounds__(256) mask_bits_kernel(
    const float* __restrict__ mask, unsigned long long* __restrict__ bits) {
  const int idx = blockIdx.x * 256 + threadIdx.x;  // 0..4095
  const int wdw = idx >> 6, m = idx & 63;
  unsigned long long bm = 0ull;
  if (m < 49) {
    const float* mp = mask + (size_t)wdw * 2401 + (size_t)m * 49;
    for (int n = 0; n < 49; ++n)
      if (mp[n] > -50.f) bm |= (1ull << n);
  }
  bits[idx] = bm;
}

// ---------------------------------------------------------------------------
__global__ void __launch_bounds__(512, 1) winattn_fused(
    const unsigned short* __restrict__ X,   // (4096*49, 384) bf16
    const unsigned short* __restrict__ Wq,  // (1152, 384) bf16
    const unsigned short* __restrict__ Wp,  // (384, 384) bf16
    const float* __restrict__ bq,           // (1152,)
    const float* __restrict__ bp,           // (384,)
    const unsigned long long* __restrict__ mbits,  // (64, 64) row bitmasks
    unsigned short* __restrict__ Og,        // (4096*49, 384) bf16 scratch
    float* __restrict__ out) {              // (4096*49, 384) fp32
  // LDS arena: As dbuf 2x16KB @0 | QK 64KB @32768 (per (wi,h): Q 4KB + K 4KB,
  // P aliases the 8KB after S) | Vt 32KB @98304 (per (wi,h): 4KB)
  __shared__ __align__(16) char lds[131072];
  char* Asb = lds;
  char* QK  = lds + 32768;
  char* VT  = lds + 98304;

  const int tid = threadIdx.x;
  const int lane = tid & 63, w = tid >> 6;
  const int l15 = lane & 15, l4 = lane >> 4;
  const int wi = w >> 2;       // window within block (0/1)
  const int wq4 = w & 3;       // col-quarter / head-lane
  const int b0 = blockIdx.x * 2;
  const int b = b0 + wi;
  const int wcol0 = wq4 * 96;

  const facc4 fz = {0.f, 0.f, 0.f, 0.f};
  const bfrag8 z8 = {0, 0, 0, 0, 0, 0, 0, 0};

  // staging map: 1024 16B chunks of a [128 rows][64 k] tile; 2 per thread.
  // HW: LDS dest = wave-uniform base + lane*16 -> chunk c = w*64 + i*512 + lane.
  // Global source is per-lane, pre-swizzled (scc = cc ^ (row&7)).
  size_t srow[2];
#pragma unroll
  for (int i = 0; i < 2; ++i) {
    const int c = tid + (i << 9);
    const int row = c >> 3, cc = c & 7;
    const int scc = cc ^ (row & 7);
    const int rwi = row >> 6;
    int n = row & 63; if (n > 48) n = 48;        // clamp pad rows (finite dup)
    srow[i] = (size_t)((b0 + rwi) * 49 + n) * 384 + scc * 8;
  }

  // ---------------- phase 1: head-groups ----------------
  for (int hg = 0; hg < 3; ++hg) {
    // zero Vt (pad cols n in [49,64) must be 0 for PV)
    {
      char* p = VT + tid * 64;
#pragma unroll
      for (int j = 0; j < 4; ++j) *(bfrag8*)(p + j * 16) = z8;
    }

    // per-fragment B pointers / bias / scatter descriptors
    const unsigned short* bptr[6];
    float bv[6], scf[6];
    int stp[6];           // strip 0=Q 1=K 2=V
    char* dbase[6];       // LDS dest base per frag
    int d0v[6];
#pragma unroll
    for (int f = 0; f < 6; ++f) {
      const int vc0 = wcol0 + f * 16;
      const int s = vc0 >> 7;
      const int c0 = vc0 & 127;
      const int hl = c0 >> 5;
      const int gcol = s * 384 + hg * 128 + c0 + l15;
      bptr[f] = Wq + (size_t)gcol * 384;
      bv[f] = bq[gcol];
      scf[f] = (s == 0) ? SCALE_Q : 1.0f;
      stp[f] = s;
      d0v[f] = c0 & 31;
      if (s < 2) dbase[f] = QK + (size_t)(wi * 4 + hl) * 8192 + s * 4096;
      else       dbase[f] = VT + (size_t)(wi * 4 + hl) * 4096;
    }

    facc4 acc[4][6];
#pragma unroll
    for (int mi = 0; mi < 4; ++mi)
#pragma unroll
      for (int f = 0; f < 6; ++f) acc[mi][f] = fz;

    // K-loop, double-buffered, stage-before-compute
    int cur = 0;
#pragma unroll
    for (int i = 0; i < 2; ++i) {
      const int lb = __builtin_amdgcn_readfirstlane((w << 10) + (i << 13));
      gload_lds16(X + srow[i], Asb + lb);
    }
    __syncthreads();
    for (int kt = 0; kt < 6; ++kt) {
      if (kt < 5) {
#pragma unroll
        for (int i = 0; i < 2; ++i) {
          const int lb = __builtin_amdgcn_readfirstlane(
              ((cur ^ 1) << 14) + (w << 10) + (i << 13));
          gload_lds16(X + srow[i] + (kt + 1) * 64, Asb + lb);
        }
      }
#pragma unroll
      for (int kk = 0; kk < 2; ++kk) {
        bfrag8 bf[6], af[4];
#pragma unroll
        for (int f = 0; f < 6; ++f)
          bf[f] = *(const bfrag8*)(bptr[f] + kt * 64 + kk * 32 + l4 * 8);
#pragma unroll
        for (int mi = 0; mi < 4; ++mi) {
          const int row = wi * 64 + mi * 16 + l15;
          af[mi] = *(const bfrag8*)(Asb + (cur << 14) + row * 128 +
                                    (((kk * 4 + l4) ^ (row & 7)) << 4));
        }
#pragma unroll
        for (int mi = 0; mi < 4; ++mi)
#pragma unroll
          for (int f = 0; f < 6; ++f)
            acc[mi][f] = __builtin_amdgcn_mfma_f32_16x16x32_bf16(af[mi], bf[f],
                                                                 acc[mi][f], 0, 0, 0);
      }
      __syncthreads();
      cur ^= 1;
    }

    // scatter to Qs / Ks / Vt  (acc: row m = mi*16+l4*4+r, col = l15 of frag)
#pragma unroll
    for (int f = 0; f < 6; ++f) {
      const int s = stp[f];
      const int d = d0v[f] + l15;
#pragma unroll
      for (int mi = 0; mi < 4; ++mi)
#pragma unroll
        for (int r = 0; r < 4; ++r) {
          const int m = mi * 16 + l4 * 4 + r;
          const float val = (acc[mi][f][r] + bv[f]) * scf[f];
          if (s < 2) {
            *(unsigned short*)(dbase[f] + m * 64 +
                               ((d << 1) ^ ((m & 3) << 4))) = f2bf(val);
          } else if (m < 49) {
            *(unsigned short*)(dbase[f] + d * 128 +
                               ((m << 1) ^ ((d & 7) << 4))) = f2bf(val);
          }
        }
    }
    __syncthreads();

    // ---------------- attention: wave -> (window wi, head hg*4+wq4) --------
    {
      char* qb = QK + (size_t)(wi * 4 + wq4) * 8192;
      char* kb = qb + 4096;
      char* vtb = VT + (size_t)(wi * 4 + wq4) * 4096;
      char* pb = qb;  // P aliases Q+K (8KB) after S is computed
      const int h = hg * 4 + wq4;

      facc4 s[4][4];
      {
        bfrag8 qa[4], kf[4];
#pragma unroll
        for (int mi = 0; mi < 4; ++mi) {
          const int row = mi * 16 + l15;
          qa[mi] = *(const bfrag8*)(qb + row * 64 + (((l4 ^ (row & 3))) << 4));
        }
#pragma unroll
        for (int ni = 0; ni < 4; ++ni) {
          const int row = ni * 16 + l15;
          kf[ni] = *(const bfrag8*)(kb + row * 64 + (((l4 ^ (row & 3))) << 4));
        }
#pragma unroll
        for (int mi = 0; mi < 4; ++mi)
#pragma unroll
          for (int ni = 0; ni < 4; ++ni)
            s[mi][ni] = __builtin_amdgcn_mfma_f32_16x16x32_bf16(qa[mi], kf[ni], fz, 0, 0, 0);
      }

      const unsigned long long* mb = mbits + (size_t)(b & 63) * 64;
      float rinv[4][4];
#pragma unroll
      for (int mi = 0; mi < 4; ++mi)
#pragma unroll
        for (int r = 0; r < 4; ++r) {
          const int m = mi * 16 + l4 * 4 + r;
          const unsigned long long mw = mb[m];
          float mx = -1e30f;
          int ok[4];
#pragma unroll
          for (int ni = 0; ni < 4; ++ni) {
            const int n = ni * 16 + l15;
            ok[ni] = (int)((mw >> n) & 1ull);
            const float v = ok[ni] ? s[mi][ni][r] : -1e30f;
            mx = fmaxf(mx, v);
          }
          mx = fmaxf(mx, __shfl_xor(mx, 1));
          mx = fmaxf(mx, __shfl_xor(mx, 2));
          mx = fmaxf(mx, __shfl_xor(mx, 4));
          mx = fmaxf(mx, __shfl_xor(mx, 8));
          float sum = 0.f;
#pragma unroll
          for (int ni = 0; ni < 4; ++ni) {
            const float p = ok[ni] ? __expf(s[mi][ni][r] - mx) : 0.f;
            s[mi][ni][r] = p;
            sum += p;
          }
          sum += __shfl_xor(sum, 1);
          sum += __shfl_xor(sum, 2);
          sum += __shfl_xor(sum, 4);
          sum += __shfl_xor(sum, 8);
          rinv[mi][r] = 1.0f / sum;
#pragma unroll
          for (int ni = 0; ni < 4; ++ni) {
            const int n = ni * 16 + l15;
            *(unsigned short*)(pb + (((m << 7) + (n << 1)) ^ ((m & 7) << 4))) =
                f2bf(s[mi][ni][r]);
          }
        }

      facc4 o[4][2];
#pragma unroll
      for (int mi = 0; mi < 4; ++mi)
#pragma unroll
        for (int di = 0; di < 2; ++di) o[mi][di] = fz;
#pragma unroll
      for (int kk = 0; kk < 2; ++kk) {
        bfrag8 pa[4], vb[2];
#pragma unroll
        for (int mi = 0; mi < 4; ++mi) {
          const int row = mi * 16 + l15;
          pa[mi] = *(const bfrag8*)(pb + (((row << 7) + kk * 64 + (l4 << 4)) ^
                                          ((row & 7) << 4)));
        }
#pragma unroll
        for (int di = 0; di < 2; ++di) {
          const int row = di * 16 + l15;
          vb[di] = *(const bfrag8*)(vtb + (((row << 7) + kk * 64 + (l4 << 4)) ^
                                           ((row & 7) << 4)));
        }
#pragma unroll
        for (int mi = 0; mi < 4; ++mi)
#pragma unroll
          for (int di = 0; di < 2; ++di)
            o[mi][di] = __builtin_amdgcn_mfma_f32_16x16x32_bf16(pa[mi], vb[di],
                                                                o[mi][di], 0, 0, 0);
      }

      unsigned short* op = Og + ((size_t)b * 49) * 384 + h * 32;
#pragma unroll
      for (int mi = 0; mi < 4; ++mi)
#pragma unroll
        for (int r = 0; r < 4; ++r) {
          const int m = mi * 16 + l4 * 4 + r;
          if (m < 49) {
            const float rs = rinv[mi][r];
#pragma unroll
            for (int di = 0; di < 2; ++di)
              op[(size_t)m * 384 + di * 16 + l15] = f2bf(o[mi][di][r] * rs);
          }
        }
    }
    __syncthreads();  // drains O writes; protects Q/K/Vt reuse next hg
  }

  // ---------------- phase 2: proj GEMM ----------------
  {
    const unsigned short* cptr[6];
    float bpv[6];
#pragma unroll
    for (int f = 0; f < 6; ++f) {
      const int c = wcol0 + f * 16 + l15;
      cptr[f] = Wp + (size_t)c * 384;
      bpv[f] = bp[c];
    }
    facc4 acc[4][6];
#pragma unroll
    for (int mi = 0; mi < 4; ++mi)
#pragma unroll
      for (int f = 0; f < 6; ++f) acc[mi][f] = fz;

    int cur = 0;
#pragma unroll
    for (int i = 0; i < 2; ++i) {
      const int lb = __builtin_amdgcn_readfirstlane((w << 10) + (i << 13));
      gload_lds16(Og + srow[i], Asb + lb);
    }
    __syncthreads();
    for (int kt = 0; kt < 6; ++kt) {
      if (kt < 5) {
#pragma unroll
        for (int i = 0; i < 2; ++i) {
          const int lb = __builtin_amdgcn_readfirstlane(
              ((cur ^ 1) << 14) + (w << 10) + (i << 13));
          gload_lds16(Og + srow[i] + (kt + 1) * 64, Asb + lb);
        }
      }
#pragma unroll
      for (int kk = 0; kk < 2; ++kk) {
        bfrag8 bf[6], af[4];
#pragma unroll
        for (int f = 0; f < 6; ++f)
          bf[f] = *(const bfrag8*)(cptr[f] + kt * 64 + kk * 32 + l4 * 8);
#pragma unroll
        for (int mi = 0; mi < 4; ++mi) {
          const int row = wi * 64 + mi * 16 + l15;
          af[mi] = *(const bfrag8*)(Asb + (cur << 14) + row * 128 +
                                    (((kk * 4 + l4) ^ (row & 7)) << 4));
        }
#pragma unroll
        for (int mi = 0; mi < 4; ++mi)
#pragma unroll
          for (int f = 0; f < 6; ++f)
            acc[mi][f] = __builtin_amdgcn_mfma_f32_16x16x32_bf16(af[mi], bf[f],
                                                                 acc[mi][f], 0, 0, 0);
      }
      __syncthreads();
      cur ^= 1;
    }

#pragma unroll
    for (int mi = 0; mi < 4; ++mi)
#pragma unroll
      for (int r = 0; r < 4; ++r) {
        const int n = mi * 16 + l4 * 4 + r;
        if (n < 49) {
          float* orow = out + ((size_t)b * 49 + n) * 384 + wcol0 + l15;
#pragma unroll
          for (int f = 0; f < 6; ++f) orow[f * 16] = acc[mi][f][r] + bpv[f];
        }
      }
  }
}

// ---------------------------------------------------------------------------
extern "C" void kernel_launch(void* const* d_in, const int* in_sizes, int n_in,
                              void* d_out, int out_size, void* d_ws, size_t ws_size,
                              hipStream_t stream) {
  const float* x      = (const float*)d_in[0];  // (4096, 49, 384)
  const float* mask   = (const float*)d_in[1];  // (64, 49, 49)
  const float* w_qkv  = (const float*)d_in[2];  // (1152, 384)
  const float* b_qkv  = (const float*)d_in[3];  // (1152,)
  const float* w_proj = (const float*)d_in[4];  // (384, 384)
  const float* b_proj = (const float*)d_in[5];  // (384,)
  float* out = (float*)d_out;

  const size_t E = 77070336ull;  // 200704*384
  unsigned short* wsu  = (unsigned short*)d_ws;
  unsigned short* o_ws = wsu;            // (200704, 384) bf16
  unsigned short* xbf  = wsu + E;        // (200704, 384) bf16
  unsigned short* wqb  = wsu + 2 * E;    // (1152, 384) bf16
  unsigned short* wpb  = wqb + 442368ull;
  unsigned long long* mb = (unsigned long long*)(wpb + 147456ull);  // 4096 u64
  const size_t need = (2 * E + 442368ull + 147456ull) * 2ull + 4096ull * 8ull;
  if (ws_size < need) {
    fprintf(stderr, "[WindowAttention] ws too small: need=%zu have=%zu\n",
            (size_t)need, ws_size);
    return;
  }

  cvt_bf16_kernel<<<75264, 256, 0, stream>>>(x, xbf);
  cvt_bf16_kernel<<<432, 256, 0, stream>>>(w_qkv, wqb);
  cvt_bf16_kernel<<<144, 256, 0, stream>>>(w_proj, wpb);
  mask_bits_kernel<<<16, 256, 0, stream>>>(mask, mb);

  winattn_fused<<<2048, 512, 0, stream>>>(xbf, wqb, wpb, b_qkv, b_proj, mb,
                                          o_ws, out);
}

// Round 7
// 824.260 us; speedup vs baseline: 2.8307x; 2.4462x over previous
//
#include <hip/hip_runtime.h>
#include <cstdio>
#include <cstdint>

// ---------------------------------------------------------------------------
// WindowAttention split pipeline, round 7 (= round 6 + Vt zero-fill fix):
//   cvt(x,wq,wp) + mask_bits
//   gemm_ak<9,0>: qkv = x @ Wqkv^T + b  -> planar (t,h,b,n,d) bf16
//       A-tile (128 rows x full K=384) persistent in LDS, staged once;
//       B streamed per (bn,kt) double-buffered with prefetch.
//   attn: per (b,h) 1 wave; Q/K frags direct from global (planar, coalesced),
//       V staged->Vt LDS, bitmask softmax, P via LDS, O -> (b,n,C) bf16
//   gemm_ak<3,1>: out = O @ Wproj^T + b -> fp32
// Round-6 bug: Vt zero-fill covered only 2KB of 4KB -> uninit LDS rows
// d in [16,32) x cols n in [49,64) fed PV MFMA -> 0*Inf = NaN. Fix: i<4.
// ---------------------------------------------------------------------------

typedef __attribute__((ext_vector_type(8))) short bfrag8;  // 8 bf16
typedef __attribute__((ext_vector_type(4))) float facc4;   // MFMA acc

#define SCALE_Q 0.17677669529663687f
#define PLANE 6422528ull  // 200704 * 32 elems per (t,h) plane

__device__ __forceinline__ unsigned short f2bf(float f) {  // fp32->bf16 RNE
  unsigned int x = __float_as_uint(f);
  x += 0x7fffu + ((x >> 16) & 1u);
  return (unsigned short)(x >> 16);
}

__device__ __forceinline__ void gload_lds16(const void* g, void* l) {
  __builtin_amdgcn_global_load_lds(
      (const __attribute__((address_space(1))) unsigned int*)g,
      (__attribute__((address_space(3))) unsigned int*)l,
      16, 0, 0);
}

// ---- fp32 -> bf16, 4 elems/thread (counts are exact multiples of 1024) ----
__global__ void __launch_bounds__(256) cvt_bf16_kernel(const float* __restrict__ src,
                                                       unsigned short* __restrict__ dst) {
  size_t i = ((size_t)blockIdx.x * 256u + threadIdx.x) * 4u;
  const float4 v = *(const float4*)(src + i);
  ushort4 o;
  o.x = f2bf(v.x); o.y = f2bf(v.y); o.z = f2bf(v.z); o.w = f2bf(v.w);
  *(ushort4*)(dst + i) = o;
}

// ---- mask -> per-row 49-bit allow mask (64 windows x 64 rows, pads=0) -----
__global__ void __launch_bounds__(256) mask_bits_kernel(
    const float* __restrict__ mask, unsigned long long* __restrict__ bits) {
  const int idx = blockIdx.x * 256 + threadIdx.x;  // 0..4095
  const int wdw = idx >> 6, m = idx & 63;
  unsigned long long bm = 0ull;
  if (m < 49) {
    const float* mp = mask + (size_t)wdw * 2401 + (size_t)m * 49;
    for (int n = 0; n < 49; ++n)
      if (mp[n] > -50.f) bm |= (1ull << n);
  }
  bits[idx] = bm;
}

// ---------------------------------------------------------------------------
// GEMM C = A * B^T (+bias). A [200704 x 384] bf16 rows, B [NBN*128 x 384] bf16
// weight rows. Per block: 128 A-rows with FULL K resident in LDS (96KB,
// XOR-swizzled 16B chunks: physical chunk pc of row holds logical lc =
// pc ^ (row&7), 48 chunks/row), bn-loop over NBN column tiles with B
// double-buffered (2x16KB, logical chunk cc at physical cc^(row&7)).
// 8 waves = 2(M) x 4(N); wave tile 64 x 32; acc[4][2].
// MODE 0: planar qkv epilogue (+bias, Q*scale). MODE 1: fp32 out (+bias).
// ---------------------------------------------------------------------------
__device__ __forceinline__ void stage_B_tile(const unsigned short* __restrict__ B,
                                             int bn, int kt, char* lbase,
                                             int tid, int w) {
#pragma unroll
  for (int i = 0; i < 2; ++i) {
    const int c = tid + (i << 9);          // 0..1023
    const int row = c >> 3, cc = c & 7;
    const int scc = cc ^ (row & 7);        // pre-swizzled source chunk
    const unsigned short* gb = B + (size_t)(bn * 128 + row) * 384 + kt * 64 + scc * 8;
    char* lb = lbase + (((w << 6) + (i << 9)) << 4);  // wave-uniform base
    gload_lds16(gb, lb);
  }
}

template <int NBN, int MODE, int SWZ>
__global__ void __launch_bounds__(512, 1) gemm_ak(
    const unsigned short* __restrict__ A, const unsigned short* __restrict__ B,
    const float* __restrict__ bias,
    unsigned short* __restrict__ qkv, float* __restrict__ f_out) {
  __shared__ __align__(16) unsigned short Alds[128 * 384];   // 96 KB
  __shared__ __align__(16) unsigned short Blds[2][128 * 64]; // 2 x 16 KB

  int bid = blockIdx.x;
  bid = (bid & 7) * SWZ + (bid >> 3);      // XCD-contiguous
  const int bm = bid;
  const int tid = threadIdx.x;
  const int lane = tid & 63, w = tid >> 6;
  const int wr = w >> 2, wc = w & 3;       // 2 x 4 waves
  const int l15 = lane & 15, l4 = lane >> 4;
  const size_t a_row0 = (size_t)bm * 128;
  const facc4 fz = {0.f, 0.f, 0.f, 0.f};

  // ---- stage A full-K: 6144 chunks of 16B, 12 per thread ----
#pragma unroll
  for (int j = 0; j < 12; ++j) {
    const int g = tid + (j << 9);
    const int row = g / 48, pc = g - row * 48;
    const int lc = pc ^ (row & 7);         // source logical chunk
    const unsigned short* ga = A + (a_row0 + row) * 384 + lc * 8;
    char* la = (char*)Alds + (((w << 6) + (j << 9)) << 4);  // wave-uniform
    gload_lds16(ga, la);
  }
  stage_B_tile(B, 0, 0, (char*)Blds[0], tid, w);
  __syncthreads();

  int cur = 0;
  for (int bn = 0; bn < NBN; ++bn) {
    facc4 acc[4][2];
#pragma unroll
    for (int mi = 0; mi < 4; ++mi)
#pragma unroll
      for (int ni = 0; ni < 2; ++ni) acc[mi][ni] = fz;

    for (int kt = 0; kt < 6; ++kt) {
      if (!(bn == NBN - 1 && kt == 5)) {
        const int nbn = (kt == 5) ? bn + 1 : bn;
        const int nkt = (kt == 5) ? 0 : kt + 1;
        stage_B_tile(B, nbn, nkt, (char*)Blds[cur ^ 1], tid, w);
      }
#pragma unroll
      for (int kk = 0; kk < 2; ++kk) {
        bfrag8 af[4], bf[2];
        const int lc = kt * 8 + kk * 4 + l4;   // logical A chunk (0..47)
#pragma unroll
        for (int mi = 0; mi < 4; ++mi) {
          const int row = wr * 64 + mi * 16 + l15;
          const int pc = lc ^ (row & 7);
          af[mi] = *(const bfrag8*)((const char*)Alds + row * 768 + pc * 16);
        }
#pragma unroll
        for (int ni = 0; ni < 2; ++ni) {
          const int rowb = wc * 32 + ni * 16 + l15;
          const int ch = (kk * 4 + l4) ^ (rowb & 7);
          bf[ni] = *(const bfrag8*)((const char*)Blds[cur] + rowb * 128 + ch * 16);
        }
#pragma unroll
        for (int mi = 0; mi < 4; ++mi)
#pragma unroll
          for (int ni = 0; ni < 2; ++ni)
            acc[mi][ni] = __builtin_amdgcn_mfma_f32_16x16x32_bf16(
                af[mi], bf[ni], acc[mi][ni], 0, 0, 0);
      }
      __syncthreads();
      cur ^= 1;
    }

    // ---- epilogue for this bn ----
    if (MODE == 0) {
#pragma unroll
      for (int ni = 0; ni < 2; ++ni) {
        const int j = bn * 128 + wc * 32 + ni * 16;   // multiple of 16
        const int t = j / 384;
        const int rj = j - t * 384;
        const int h = rj >> 5, dd = rj & 31;          // dd in {0,16}
        unsigned short* pl = qkv + (size_t)(t * 12 + h) * PLANE + dd + l15;
        const float bvv = bias[j + l15];
        const float sc = (t == 0) ? SCALE_Q : 1.0f;
#pragma unroll
        for (int mi = 0; mi < 4; ++mi)
#pragma unroll
          for (int r = 0; r < 4; ++r) {
            const size_t m = a_row0 + wr * 64 + mi * 16 + l4 * 4 + r;
            pl[m * 32] = f2bf((acc[mi][ni][r] + bvv) * sc);
          }
      }
    } else {
#pragma unroll
      for (int ni = 0; ni < 2; ++ni) {
        const int col = bn * 128 + wc * 32 + ni * 16 + l15;
        const float bvv = bias[col];
#pragma unroll
        for (int mi = 0; mi < 4; ++mi)
#pragma unroll
          for (int r = 0; r < 4; ++r) {
            const size_t m = a_row0 + wr * 64 + mi * 16 + l4 * 4 + r;
            f_out[m * 384 + col] = acc[mi][ni][r] + bvv;
          }
      }
    }
  }
}

// ---------------------------------------------------------------------------
// Attention: one wave per (window b, head h). Planar Q/K/V: per (t,h) plane
// of [200704 x 32] bf16; this head's window slab is 49x32 contiguous.
// Q/K MFMA fragments loaded DIRECT from global (1KB-coalesced, L3-hit).
// V staged to LDS transposed+swizzled; P via LDS; bitmask softmax.
// Rows/cols >= 49 read neighbor-window data -> masked to zero contribution.
// ---------------------------------------------------------------------------
__global__ void __launch_bounds__(64) attn_kernel(
    const unsigned short* __restrict__ QKV,        // 36 planes
    const unsigned long long* __restrict__ mbits,  // (64, 64)
    unsigned short* __restrict__ Og) {             // (4096*49, 384) bf16
  __shared__ unsigned short Vt[32 * 64];   // [d][n], byte-XOR swizzled
  __shared__ unsigned short Ps[64 * 64];   // [m][n], byte-XOR swizzled

  const int bid = blockIdx.x;
  const int b = bid / 12, h = bid - b * 12;
  const int lane = threadIdx.x;
  const int l15 = lane & 15, l4 = lane >> 4;

  const bfrag8 z8 = {0, 0, 0, 0, 0, 0, 0, 0};
  const facc4 fz = {0.f, 0.f, 0.f, 0.f};

  const size_t wb = (size_t)b * 49 * 32;
  const unsigned short* Qp = QKV + (size_t)h * PLANE + wb;
  const unsigned short* Kp = QKV + (size_t)(12 + h) * PLANE + wb;
  const unsigned short* Vp = QKV + (size_t)(24 + h) * PLANE + wb;

  // zero ALL of Vt (4096 B = 256 chunks): pad cols n in [49,64) must be 0
#pragma unroll
  for (int i = 0; i < 4; ++i)
    *(bfrag8*)((char*)Vt + (lane + i * 64) * 16) = z8;

  // stage V -> Vt transposed (196 real 16B chunks)
#pragma unroll
  for (int i = 0; i < 4; ++i) {
    const int c = lane + i * 64;
    if (c < 196) {
      const bfrag8 vv = *(const bfrag8*)(Vp + c * 8);
      const int n = c >> 2, cc = c & 3;
      const int d0 = cc * 8;
#pragma unroll
      for (int jj = 0; jj < 8; ++jj) {
        const int d = d0 + jj;
        *(unsigned short*)((char*)Vt + (((d << 7) + (n << 1)) ^ ((d & 7) << 4))) =
            (unsigned short)vv[jj];
      }
    }
  }
  __syncthreads();

  // S = Q K^T : frags direct from global. frag[row=l15][k=l4*8+j]
  facc4 s[4][4];
  {
    bfrag8 qa[4], kf[4];
#pragma unroll
    for (int mi = 0; mi < 4; ++mi)
      qa[mi] = *(const bfrag8*)((const char*)Qp + (mi * 16 + l15) * 64 + l4 * 16);
#pragma unroll
    for (int ni = 0; ni < 4; ++ni)
      kf[ni] = *(const bfrag8*)((const char*)Kp + (ni * 16 + l15) * 64 + l4 * 16);
#pragma unroll
    for (int mi = 0; mi < 4; ++mi)
#pragma unroll
      for (int ni = 0; ni < 4; ++ni)
        s[mi][ni] = __builtin_amdgcn_mfma_f32_16x16x32_bf16(qa[mi], kf[ni], fz, 0, 0, 0);
  }

  // bitmask softmax. acc layout: n = ni*16 + l15, m = mi*16 + l4*4 + r
  const unsigned long long* mb = mbits + (size_t)(b & 63) * 64;
  float rinv[4][4];
#pragma unroll
  for (int mi = 0; mi < 4; ++mi)
#pragma unroll
    for (int r = 0; r < 4; ++r) {
      const int m = mi * 16 + l4 * 4 + r;
      const unsigned long long mw = mb[m];
      float mx = -1e30f;
      int ok[4];
#pragma unroll
      for (int ni = 0; ni < 4; ++ni) {
        const int n = ni * 16 + l15;
        ok[ni] = (int)((mw >> n) & 1ull);
        const float v = ok[ni] ? s[mi][ni][r] : -1e30f;
        mx = fmaxf(mx, v);
      }
      mx = fmaxf(mx, __shfl_xor(mx, 1));
      mx = fmaxf(mx, __shfl_xor(mx, 2));
      mx = fmaxf(mx, __shfl_xor(mx, 4));
      mx = fmaxf(mx, __shfl_xor(mx, 8));
      float sum = 0.f;
#pragma unroll
      for (int ni = 0; ni < 4; ++ni) {
        const float p = ok[ni] ? __expf(s[mi][ni][r] - mx) : 0.f;
        s[mi][ni][r] = p;
        sum += p;
      }
      sum += __shfl_xor(sum, 1);
      sum += __shfl_xor(sum, 2);
      sum += __shfl_xor(sum, 4);
      sum += __shfl_xor(sum, 8);
      rinv[mi][r] = 1.0f / sum;
#pragma unroll
      for (int ni = 0; ni < 4; ++ni) {
        const int n = ni * 16 + l15;
        *(unsigned short*)((char*)Ps + (((m << 7) + (n << 1)) ^ ((m & 7) << 4))) =
            f2bf(s[mi][ni][r]);
      }
    }
  __syncthreads();

  // O = P V (unnormalized), then scale by 1/rowsum
  facc4 o[4][2];
#pragma unroll
  for (int mi = 0; mi < 4; ++mi)
#pragma unroll
    for (int di = 0; di < 2; ++di) o[mi][di] = fz;
#pragma unroll
  for (int kk = 0; kk < 2; ++kk) {
    bfrag8 pa[4], vb[2];
#pragma unroll
    for (int mi = 0; mi < 4; ++mi) {
      const int row = mi * 16 + l15;
      pa[mi] = *(const bfrag8*)((const char*)Ps +
                                (((row << 7) + kk * 64 + (l4 << 4)) ^ ((row & 7) << 4)));
    }
#pragma unroll
    for (int di = 0; di < 2; ++di) {
      const int row = di * 16 + l15;
      vb[di] = *(const bfrag8*)((const char*)Vt +
                                (((row << 7) + kk * 64 + (l4 << 4)) ^ ((row & 7) << 4)));
    }
#pragma unroll
    for (int mi = 0; mi < 4; ++mi)
#pragma unroll
      for (int di = 0; di < 2; ++di)
        o[mi][di] = __builtin_amdgcn_mfma_f32_16x16x32_bf16(pa[mi], vb[di], o[mi][di], 0, 0, 0);
  }

  unsigned short* op = Og + (size_t)b * 18816 + h * 32;  // (b, n, C)
#pragma unroll
  for (int mi = 0; mi < 4; ++mi)
#pragma unroll
    for (int r = 0; r < 4; ++r) {
      const int m = mi * 16 + l4 * 4 + r;
      if (m < 49) {
        const float rs = rinv[mi][r];
#pragma unroll
        for (int di = 0; di < 2; ++di)
          op[(size_t)m * 384 + di * 16 + l15] = f2bf(o[mi][di][r] * rs);
      }
    }
}

// ---------------------------------------------------------------------------
extern "C" void kernel_launch(void* const* d_in, const int* in_sizes, int n_in,
                              void* d_out, int out_size, void* d_ws, size_t ws_size,
                              hipStream_t stream) {
  const float* x      = (const float*)d_in[0];  // (4096, 49, 384)
  const float* mask   = (const float*)d_in[1];  // (64, 49, 49)
  const float* w_qkv  = (const float*)d_in[2];  // (1152, 384)
  const float* b_qkv  = (const float*)d_in[3];  // (1152,)
  const float* w_proj = (const float*)d_in[4];  // (384, 384)
  const float* b_proj = (const float*)d_in[5];  // (384,)
  float* out = (float*)d_out;

  const size_t E = 77070336ull;  // 200704*384  (3*E = 36 planes)
  unsigned short* wsu   = (unsigned short*)d_ws;
  unsigned short* qkvp  = wsu;            // planar qkv: 3E
  unsigned short* o_ws  = wsu + 3 * E;    // (200704, 384) bf16
  unsigned short* xbf   = wsu + 4 * E;    // (200704, 384) bf16
  unsigned short* wqb   = wsu + 5 * E;    // (1152, 384) bf16
  unsigned short* wpb   = wqb + 442368ull;
  unsigned long long* mb = (unsigned long long*)(wpb + 147456ull);  // 4096 u64
  const size_t need = (5 * E + 442368ull + 147456ull) * 2ull + 4096ull * 8ull;
  if (ws_size < need) {
    fprintf(stderr, "[WindowAttention] ws too small: need=%zu have=%zu\n",
            (size_t)need, ws_size);
    return;
  }

  cvt_bf16_kernel<<<75264, 256, 0, stream>>>(x, xbf);
  cvt_bf16_kernel<<<432, 256, 0, stream>>>(w_qkv, wqb);
  cvt_bf16_kernel<<<144, 256, 0, stream>>>(w_proj, wpb);
  mask_bits_kernel<<<16, 256, 0, stream>>>(mask, mb);

  // QKV projection: 1568 blocks (=8*196), N-tiles = 9
  gemm_ak<9, 0, 196><<<1568, 512, 0, stream>>>(xbf, wqb, b_qkv, qkvp, nullptr);

  // attention: one wave per (b, h)
  attn_kernel<<<49152, 64, 0, stream>>>(qkvp, mb, o_ws);

  // output projection: N-tiles = 3
  gemm_ak<3, 1, 196><<<1568, 512, 0, stream>>>(o_ws, wpb, b_proj, nullptr, out);
}

// Round 8
// 810.629 us; speedup vs baseline: 2.8783x; 1.0168x over previous
//
#include <hip/hip_runtime.h>
#include <cstdio>
#include <cstdint>

// ---------------------------------------------------------------------------
// WindowAttention split pipeline, round 8 (= round 7 + counted-vmcnt K-loop):
//   gemm_ak: A-tile (128 rows x full K=384) persistent in LDS; B streamed
//   double-buffered with counted s_waitcnt vmcnt(2) + raw s_barrier pairs
//   (prefetch loads stay in flight across barriers; never drain to 0 in-loop).
//   attn: per (b,h) 1 wave, planar QKV, bitmask softmax (unchanged, passing).
// Shapes: B=4096 N=49 C=384 H=12 HD=32 NW=64; M=200704, K=384.
// ---------------------------------------------------------------------------

typedef __attribute__((ext_vector_type(8))) short bfrag8;  // 8 bf16
typedef __attribute__((ext_vector_type(4))) float facc4;   // MFMA acc

#define SCALE_Q 0.17677669529663687f
#define PLANE 6422528ull  // 200704 * 32 elems per (t,h) plane

__device__ __forceinline__ unsigned short f2bf(float f) {  // fp32->bf16 RNE
  unsigned int x = __float_as_uint(f);
  x += 0x7fffu + ((x >> 16) & 1u);
  return (unsigned short)(x >> 16);
}

__device__ __forceinline__ void gload_lds16(const void* g, void* l) {
  __builtin_amdgcn_global_load_lds(
      (const __attribute__((address_space(1))) unsigned int*)g,
      (__attribute__((address_space(3))) unsigned int*)l,
      16, 0, 0);
}

// ---- fp32 -> bf16, 4 elems/thread (counts are exact multiples of 1024) ----
__global__ void __launch_bounds__(256) cvt_bf16_kernel(const float* __restrict__ src,
                                                       unsigned short* __restrict__ dst) {
  size_t i = ((size_t)blockIdx.x * 256u + threadIdx.x) * 4u;
  const float4 v = *(const float4*)(src + i);
  ushort4 o;
  o.x = f2bf(v.x); o.y = f2bf(v.y); o.z = f2bf(v.z); o.w = f2bf(v.w);
  *(ushort4*)(dst + i) = o;
}

// ---- mask -> per-row 49-bit allow mask (64 windows x 64 rows, pads=0) -----
__global__ void __launch_bounds__(256) mask_bits_kernel(
    const float* __restrict__ mask, unsigned long long* __restrict__ bits) {
  const int idx = blockIdx.x * 256 + threadIdx.x;  // 0..4095
  const int wdw = idx >> 6, m = idx & 63;
  unsigned long long bm = 0ull;
  if (m < 49) {
    const float* mp = mask + (size_t)wdw * 2401 + (size_t)m * 49;
    for (int n = 0; n < 49; ++n)
      if (mp[n] > -50.f) bm |= (1ull << n);
  }
  bits[idx] = bm;
}

// ---------------------------------------------------------------------------
// GEMM C = A * B^T (+bias). Per block: 128 A-rows full-K in LDS (96KB,
// XOR-swizzled), B double-buffered 2x16KB, counted-vmcnt pipeline.
// 8 waves = 2(M) x 4(N); wave tile 64 x 32; acc[4][2].
// MODE 0: planar qkv epilogue (+bias, Q*scale). MODE 1: fp32 out (+bias).
// ---------------------------------------------------------------------------
__device__ __forceinline__ void stage_B_tile(const unsigned short* __restrict__ B,
                                             int bn, int kt, char* lbase,
                                             int tid, int w) {
#pragma unroll
  for (int i = 0; i < 2; ++i) {
    const int c = tid + (i << 9);          // 0..1023
    const int row = c >> 3, cc = c & 7;
    const int scc = cc ^ (row & 7);        // pre-swizzled source chunk
    const unsigned short* gb = B + (size_t)(bn * 128 + row) * 384 + kt * 64 + scc * 8;
    char* lb = lbase + (((w << 6) + (i << 9)) << 4);  // wave-uniform base
    gload_lds16(gb, lb);
  }
}

template <int NBN, int MODE, int SWZ>
__global__ void __launch_bounds__(512, 1) gemm_ak(
    const unsigned short* __restrict__ A, const unsigned short* __restrict__ B,
    const float* __restrict__ bias,
    unsigned short* __restrict__ qkv, float* __restrict__ f_out) {
  __shared__ __align__(16) unsigned short Alds[128 * 384];   // 96 KB
  __shared__ __align__(16) unsigned short Blds[2][128 * 64]; // 2 x 16 KB

  int bid = blockIdx.x;
  bid = (bid & 7) * SWZ + (bid >> 3);      // XCD-contiguous
  const int bm = bid;
  const int tid = threadIdx.x;
  const int lane = tid & 63, w = tid >> 6;
  const int wr = w >> 2, wc = w & 3;       // 2 x 4 waves
  const int l15 = lane & 15, l4 = lane >> 4;
  const size_t a_row0 = (size_t)bm * 128;
  const facc4 fz = {0.f, 0.f, 0.f, 0.f};

  // ---- stage A full-K: 6144 chunks of 16B, 12 per thread ----
#pragma unroll
  for (int j = 0; j < 12; ++j) {
    const int g = tid + (j << 9);
    const int row = g / 48, pc = g - row * 48;
    const int lc = pc ^ (row & 7);         // source logical chunk
    const unsigned short* ga = A + (a_row0 + row) * 384 + lc * 8;
    char* la = (char*)Alds + (((w << 6) + (j << 9)) << 4);  // wave-uniform
    gload_lds16(ga, la);
  }
  stage_B_tile(B, 0, 0, (char*)Blds[0], tid, w);   // step 0
  asm volatile("s_waitcnt vmcnt(0)" ::: "memory");
  __builtin_amdgcn_s_barrier();
  __builtin_amdgcn_sched_barrier(0);
  stage_B_tile(B, 0, 1, (char*)Blds[1], tid, w);   // step 1 (in flight: 2)

  for (int bn = 0; bn < NBN; ++bn) {
    facc4 acc[4][2];
#pragma unroll
    for (int mi = 0; mi < 4; ++mi)
#pragma unroll
      for (int ni = 0; ni < 2; ++ni) acc[mi][ni] = fz;

    for (int kt = 0; kt < 6; ++kt) {
      const int step = bn * 6 + kt;
      // current tile's loads done (newest 2 = next tile's stay in flight)
      asm volatile("s_waitcnt vmcnt(2)" ::: "memory");
      __builtin_amdgcn_sched_barrier(0);
      __builtin_amdgcn_s_barrier();
      __builtin_amdgcn_sched_barrier(0);
      const char* bbuf = (const char*)Blds[step & 1];
#pragma unroll
      for (int kk = 0; kk < 2; ++kk) {
        bfrag8 af[4], bf[2];
        const int lc = kt * 8 + kk * 4 + l4;   // logical A chunk (0..47)
#pragma unroll
        for (int mi = 0; mi < 4; ++mi) {
          const int row = wr * 64 + mi * 16 + l15;
          const int pc = lc ^ (row & 7);
          af[mi] = *(const bfrag8*)((const char*)Alds + row * 768 + pc * 16);
        }
#pragma unroll
        for (int ni = 0; ni < 2; ++ni) {
          const int rowb = wc * 32 + ni * 16 + l15;
          const int ch = (kk * 4 + l4) ^ (rowb & 7);
          bf[ni] = *(const bfrag8*)(bbuf + rowb * 128 + ch * 16);
        }
#pragma unroll
        for (int mi = 0; mi < 4; ++mi)
#pragma unroll
          for (int ni = 0; ni < 2; ++ni)
            acc[mi][ni] = __builtin_amdgcn_mfma_f32_16x16x32_bf16(
                af[mi], bf[ni], acc[mi][ni], 0, 0, 0);
      }
      // all my LDS reads serviced before anyone overwrites this buffer
      asm volatile("s_waitcnt lgkmcnt(0)" ::: "memory");
      __builtin_amdgcn_sched_barrier(0);
      __builtin_amdgcn_s_barrier();
      __builtin_amdgcn_sched_barrier(0);
      const int nstep = step + 2;
      if (nstep < NBN * 6)
        stage_B_tile(B, nstep / 6, nstep % 6, (char*)Blds[step & 1], tid, w);
    }

    // ---- epilogue for this bn ----
    if (MODE == 0) {
#pragma unroll
      for (int ni = 0; ni < 2; ++ni) {
        const int j = bn * 128 + wc * 32 + ni * 16;   // multiple of 16
        const int t = j / 384;
        const int rj = j - t * 384;
        const int h = rj >> 5, dd = rj & 31;          // dd in {0,16}
        unsigned short* pl = qkv + (size_t)(t * 12 + h) * PLANE + dd + l15;
        const float bvv = bias[j + l15];
        const float sc = (t == 0) ? SCALE_Q : 1.0f;
#pragma unroll
        for (int mi = 0; mi < 4; ++mi)
#pragma unroll
          for (int r = 0; r < 4; ++r) {
            const size_t m = a_row0 + wr * 64 + mi * 16 + l4 * 4 + r;
            pl[m * 32] = f2bf((acc[mi][ni][r] + bvv) * sc);
          }
      }
    } else {
#pragma unroll
      for (int ni = 0; ni < 2; ++ni) {
        const int col = bn * 128 + wc * 32 + ni * 16 + l15;
        const float bvv = bias[col];
#pragma unroll
        for (int mi = 0; mi < 4; ++mi)
#pragma unroll
          for (int r = 0; r < 4; ++r) {
            const size_t m = a_row0 + wr * 64 + mi * 16 + l4 * 4 + r;
            f_out[m * 384 + col] = acc[mi][ni][r] + bvv;
          }
      }
    }
  }
}

// ---------------------------------------------------------------------------
// Attention: one wave per (window b, head h). Planar Q/K/V: per (t,h) plane
// of [200704 x 32] bf16; this head's window slab is 49x32 contiguous.
// Q/K MFMA fragments loaded DIRECT from global (coalesced, L2/L3-hit).
// V staged to LDS transposed+swizzled; P via LDS; bitmask softmax.
// ---------------------------------------------------------------------------
__global__ void __launch_bounds__(64) attn_kernel(
    const unsigned short* __restrict__ QKV,        // 36 planes
    const unsigned long long* __restrict__ mbits,  // (64, 64)
    unsigned short* __restrict__ Og) {             // (4096*49, 384) bf16
  __shared__ unsigned short Vt[32 * 64];   // [d][n], byte-XOR swizzled
  __shared__ unsigned short Ps[64 * 64];   // [m][n], byte-XOR swizzled

  const int bid = blockIdx.x;
  const int b = bid / 12, h = bid - b * 12;
  const int lane = threadIdx.x;
  const int l15 = lane & 15, l4 = lane >> 4;

  const bfrag8 z8 = {0, 0, 0, 0, 0, 0, 0, 0};
  const facc4 fz = {0.f, 0.f, 0.f, 0.f};

  const size_t wb = (size_t)b * 49 * 32;
  const unsigned short* Qp = QKV + (size_t)h * PLANE + wb;
  const unsigned short* Kp = QKV + (size_t)(12 + h) * PLANE + wb;
  const unsigned short* Vp = QKV + (size_t)(24 + h) * PLANE + wb;

  // zero ALL of Vt (4096 B = 256 chunks): pad cols n in [49,64) must be 0
#pragma unroll
  for (int i = 0; i < 4; ++i)
    *(bfrag8*)((char*)Vt + (lane + i * 64) * 16) = z8;

  // stage V -> Vt transposed (196 real 16B chunks)
#pragma unroll
  for (int i = 0; i < 4; ++i) {
    const int c = lane + i * 64;
    if (c < 196) {
      const bfrag8 vv = *(const bfrag8*)(Vp + c * 8);
      const int n = c >> 2, cc = c & 3;
      const int d0 = cc * 8;
#pragma unroll
      for (int jj = 0; jj < 8; ++jj) {
        const int d = d0 + jj;
        *(unsigned short*)((char*)Vt + (((d << 7) + (n << 1)) ^ ((d & 7) << 4))) =
            (unsigned short)vv[jj];
      }
    }
  }
  __syncthreads();

  // S = Q K^T : frags direct from global. frag[row=l15][k=l4*8+j]
  facc4 s[4][4];
  {
    bfrag8 qa[4], kf[4];
#pragma unroll
    for (int mi = 0; mi < 4; ++mi)
      qa[mi] = *(const bfrag8*)((const char*)Qp + (mi * 16 + l15) * 64 + l4 * 16);
#pragma unroll
    for (int ni = 0; ni < 4; ++ni)
      kf[ni] = *(const bfrag8*)((const char*)Kp + (ni * 16 + l15) * 64 + l4 * 16);
#pragma unroll
    for (int mi = 0; mi < 4; ++mi)
#pragma unroll
      for (int ni = 0; ni < 4; ++ni)
        s[mi][ni] = __builtin_amdgcn_mfma_f32_16x16x32_bf16(qa[mi], kf[ni], fz, 0, 0, 0);
  }

  // bitmask softmax. acc layout: n = ni*16 + l15, m = mi*16 + l4*4 + r
  const unsigned long long* mb = mbits + (size_t)(b & 63) * 64;
  float rinv[4][4];
#pragma unroll
  for (int mi = 0; mi < 4; ++mi)
#pragma unroll
    for (int r = 0; r < 4; ++r) {
      const int m = mi * 16 + l4 * 4 + r;
      const unsigned long long mw = mb[m];
      float mx = -1e30f;
      int ok[4];
#pragma unroll
      for (int ni = 0; ni < 4; ++ni) {
        const int n = ni * 16 + l15;
        ok[ni] = (int)((mw >> n) & 1ull);
        const float v = ok[ni] ? s[mi][ni][r] : -1e30f;
        mx = fmaxf(mx, v);
      }
      mx = fmaxf(mx, __shfl_xor(mx, 1));
      mx = fmaxf(mx, __shfl_xor(mx, 2));
      mx = fmaxf(mx, __shfl_xor(mx, 4));
      mx = fmaxf(mx, __shfl_xor(mx, 8));
      float sum = 0.f;
#pragma unroll
      for (int ni = 0; ni < 4; ++ni) {
        const float p = ok[ni] ? __expf(s[mi][ni][r] - mx) : 0.f;
        s[mi][ni][r] = p;
        sum += p;
      }
      sum += __shfl_xor(sum, 1);
      sum += __shfl_xor(sum, 2);
      sum += __shfl_xor(sum, 4);
      sum += __shfl_xor(sum, 8);
      rinv[mi][r] = 1.0f / sum;
#pragma unroll
      for (int ni = 0; ni < 4; ++ni) {
        const int n = ni * 16 + l15;
        *(unsigned short*)((char*)Ps + (((m << 7) + (n << 1)) ^ ((m & 7) << 4))) =
            f2bf(s[mi][ni][r]);
      }
    }
  __syncthreads();

  // O = P V (unnormalized), then scale by 1/rowsum
  facc4 o[4][2];
#pragma unroll
  for (int mi = 0; mi < 4; ++mi)
#pragma unroll
    for (int di = 0; di < 2; ++di) o[mi][di] = fz;
#pragma unroll
  for (int kk = 0; kk < 2; ++kk) {
    bfrag8 pa[4], vb[2];
#pragma unroll
    for (int mi = 0; mi < 4; ++mi) {
      const int row = mi * 16 + l15;
      pa[mi] = *(const bfrag8*)((const char*)Ps +
                                (((row << 7) + kk * 64 + (l4 << 4)) ^ ((row & 7) << 4)));
    }
#pragma unroll
    for (int di = 0; di < 2; ++di) {
      const int row = di * 16 + l15;
      vb[di] = *(const bfrag8*)((const char*)Vt +
                                (((row << 7) + kk * 64 + (l4 << 4)) ^ ((row & 7) << 4)));
    }
#pragma unroll
    for (int mi = 0; mi < 4; ++mi)
#pragma unroll
      for (int di = 0; di < 2; ++di)
        o[mi][di] = __builtin_amdgcn_mfma_f32_16x16x32_bf16(pa[mi], vb[di], o[mi][di], 0, 0, 0);
  }

  unsigned short* op = Og + (size_t)b * 18816 + h * 32;  // (b, n, C)
#pragma unroll
  for (int mi = 0; mi < 4; ++mi)
#pragma unroll
    for (int r = 0; r < 4; ++r) {
      const int m = mi * 16 + l4 * 4 + r;
      if (m < 49) {
        const float rs = rinv[mi][r];
#pragma unroll
        for (int di = 0; di < 2; ++di)
          op[(size_t)m * 384 + di * 16 + l15] = f2bf(o[mi][di][r] * rs);
      }
    }
}

// ---------------------------------------------------------------------------
extern "C" void kernel_launch(void* const* d_in, const int* in_sizes, int n_in,
                              void* d_out, int out_size, void* d_ws, size_t ws_size,
                              hipStream_t stream) {
  const float* x      = (const float*)d_in[0];  // (4096, 49, 384)
  const float* mask   = (const float*)d_in[1];  // (64, 49, 49)
  const float* w_qkv  = (const float*)d_in[2];  // (1152, 384)
  const float* b_qkv  = (const float*)d_in[3];  // (1152,)
  const float* w_proj = (const float*)d_in[4];  // (384, 384)
  const float* b_proj = (const float*)d_in[5];  // (384,)
  float* out = (float*)d_out;

  const size_t E = 77070336ull;  // 200704*384  (3*E = 36 planes)
  unsigned short* wsu   = (unsigned short*)d_ws;
  unsigned short* qkvp  = wsu;            // planar qkv: 3E
  unsigned short* o_ws  = wsu + 3 * E;    // (200704, 384) bf16
  unsigned short* xbf   = wsu + 4 * E;    // (200704, 384) bf16
  unsigned short* wqb   = wsu + 5 * E;    // (1152, 384) bf16
  unsigned short* wpb   = wqb + 442368ull;
  unsigned long long* mb = (unsigned long long*)(wpb + 147456ull);  // 4096 u64
  const size_t need = (5 * E + 442368ull + 147456ull) * 2ull + 4096ull * 8ull;
  if (ws_size < need) {
    fprintf(stderr, "[WindowAttention] ws too small: need=%zu have=%zu\n",
            (size_t)need, ws_size);
    return;
  }

  cvt_bf16_kernel<<<75264, 256, 0, stream>>>(x, xbf);
  cvt_bf16_kernel<<<432, 256, 0, stream>>>(w_qkv, wqb);
  cvt_bf16_kernel<<<144, 256, 0, stream>>>(w_proj, wpb);
  mask_bits_kernel<<<16, 256, 0, stream>>>(mask, mb);

  // QKV projection: 1568 blocks (=8*196), N-tiles = 9
  gemm_ak<9, 0, 196><<<1568, 512, 0, stream>>>(xbf, wqb, b_qkv, qkvp, nullptr);

  // attention: one wave per (b, h)
  attn_kernel<<<49152, 64, 0, stream>>>(qkvp, mb, o_ws);

  // output projection: N-tiles = 3
  gemm_ak<3, 1, 196><<<1568, 512, 0, stream>>>(o_ws, wpb, b_proj, nullptr, out);
}